// Round 5
// baseline (163.641 us; speedup 1.0000x reference)
//
#include <hip/hip_runtime.h>
#include <hip/hip_bf16.h>

#define B_ 2
#define C_ 256
#define H_ 64
#define W_ 64
#define N_ 4096  // H_*W_

typedef short bf16x8 __attribute__((ext_vector_type(8)));
typedef _Float16 f16x8 __attribute__((ext_vector_type(8)));
typedef float f32x4 __attribute__((ext_vector_type(4)));
typedef float f32x16 __attribute__((ext_vector_type(16)));

// float -> bf16 (round to nearest even), finite inputs
static __device__ __forceinline__ unsigned short f2bf(float f) {
    union { float f; unsigned u; } uf; uf.f = f;
    unsigned r = uf.u + 0x7fffu + ((uf.u >> 16) & 1u);
    return (unsigned short)(r >> 16);
}
// float -> fp16 bits
static __device__ __forceinline__ unsigned short f2h_u(float f) {
    union { _Float16 h; unsigned short u; } c; c.h = (_Float16)f; return c.u;
}

// async global->LDS, 16B per lane. LDS dest must be wave-uniform base + lane*16.
static __device__ __forceinline__ void gload16(const void* g, void* l) {
    __builtin_amdgcn_global_load_lds(
        (const __attribute__((address_space(1))) unsigned int*)g,
        (__attribute__((address_space(3))) unsigned int*)l, 16, 0, 0);
}

// ---------------------------------------------------------------------------
// Prep: [B][C][N] f32 -> [B][N][C] fp16, both inputs in one launch.
// ---------------------------------------------------------------------------
__global__ __launch_bounds__(256) void cvt_x_k(const float* __restrict__ x,
                                               const float* __restrict__ ref_x,
                                               unsigned short* __restrict__ xtx,
                                               unsigned short* __restrict__ xtr)
{
    __shared__ unsigned short t[64][72];
    const int pt = blockIdx.x, ct = blockIdx.y;
    const int which = blockIdx.z >> 1, b = blockIdx.z & 1;
    const float* in = which ? ref_x : x;
    unsigned short* out = which ? xtr : xtx;
    const int a = threadIdx.x & 63, r = threadIdx.x >> 6;
    #pragma unroll
    for (int i = 0; i < 16; ++i) {
        int c = i * 4 + r;
        t[c][a] = f2h_u(in[((size_t)(b * C_ + ct * 64 + c) << 12) + pt * 64 + a]);
    }
    __syncthreads();
    #pragma unroll
    for (int i = 0; i < 16; ++i) {
        int p = i * 4 + r;
        out[((size_t)(b * N_ + pt * 64 + p) << 8) + ct * 64 + a] = t[a][p];
    }
}

// Prep: both weights [O][I][3][3] f32 -> [tap][O][I] fp16 in one launch
__global__ __launch_bounds__(256) void cvt_w_k(const float* __restrict__ w1,
                                               const float* __restrict__ w2,
                                               unsigned short* __restrict__ wh1,
                                               unsigned short* __restrict__ wh2)
{
    int g = blockIdx.x;
    const float* w = (g < 2304) ? w1 : w2;
    unsigned short* wh = (g < 2304) ? wh1 : wh2;
    int i = (g % 2304) * 256 + threadIdx.x;         // < 9*256*256 exactly
    int ci = i & 255, co = (i >> 8) & 255, tap = i >> 16;
    wh[i] = f2h_u(w[((size_t)(co * 256 + ci)) * 9 + tap]);
}

// ---------------------------------------------------------------------------
// Implicit-GEMM 3x3 SAME conv + bias + relu via MFMA 32x32x16 fp16.
// Block: 64 cout x 256 pos (4 plane rows). 4 waves, wave w owns plane row
// r0+w (64 pos), full 64 co -> 2x2 frags of 32x32. z = cid*2+b as before.
// 32x32x16 halves LDS bytes/FLOP vs 16x16x32 (2KB feeds 32 KFLOP).
// ---------------------------------------------------------------------------
__global__ __launch_bounds__(256) void conv_mfma_k(
    const unsigned short* __restrict__ xtx, const unsigned short* __restrict__ xtr,
    const unsigned short* __restrict__ w1h, const unsigned short* __restrict__ w2h,
    const float* __restrict__ b1, const float* __restrict__ b2,
    unsigned short* __restrict__ f1x, unsigned short* __restrict__ f1r,
    unsigned short* __restrict__ f2)
{
    __shared__ unsigned short As[9 * 64 * 32];   // [tap][co64][k32] linear, 36 KB
    __shared__ unsigned short Bs[6 * 66 * 32];   // [row6][col66][k32 swz] 25.3 KB
    const int tid = threadIdx.x;
    const int pt  = blockIdx.x;   // 0..15 : plane rows pt*4 .. pt*4+3
    const int cot = blockIdx.y;   // 0..3
    const int cid = blockIdx.z >> 1;
    const int b   = blockIdx.z & 1;

    const unsigned short* xt = (cid == 1) ? xtr : xtx;
    const unsigned short* wt = (cid == 2) ? w2h : w1h;
    const float* bias = (cid == 2) ? b2 : b1;
    unsigned short* out = (cid == 0) ? f1x : (cid == 1) ? f1r : f2;
    const int trans = (cid != 2);

    const int lane = tid & 63, wid = tid >> 6;
    const int rl32 = lane & 31, l5 = lane >> 5;
    const int r0 = pt * 4;

    f32x16 acc[2][2];
    #pragma unroll
    for (int fm = 0; fm < 2; ++fm)
        #pragma unroll
        for (int fn = 0; fn < 2; ++fn)
            #pragma unroll
            for (int e = 0; e < 16; ++e) acc[fm][fn][e] = 0.f;

    for (int k0 = 0; k0 < C_; k0 += 32) {
        // stage A via global_load_lds: linear [tap][co][k]; per tap, thread tid
        // stages 16B chunk (co=tid>>2, kq=tid&3) -> dest = base + lane*16B.
        #pragma unroll
        for (int tap = 0; tap < 9; ++tap) {
            gload16(wt + ((size_t)(tap * C_ + cot * 64 + wid * 16 + (lane >> 2)) << 8)
                       + k0 + (lane & 3) * 8,
                    &As[tap * 2048 + wid * 512 + lane * 8]);
        }
        // stage B: 6*66*4 = 1584 16B chunks (zero-padded halo), chunk-swizzled
        #pragma unroll
        for (int j = 0; j < 7; ++j) {
            int it = tid + j * 256;
            if (it < 1584) {
                int col = it / 24;                 // 0..65
                int rem = it - col * 24;
                int row = rem >> 2, qb = rem & 3;  // row 0..5
                int h = r0 + row - 1, c = col - 1;
                float4 v; v.x = 0.f; v.y = 0.f; v.z = 0.f; v.w = 0.f;
                if (h >= 0 && h < 64 && c >= 0 && c < 64)
                    v = *(const float4*)(xt + ((size_t)(b * N_ + h * 64 + c) << 8) + k0 + qb * 8);
                int chunk = qb ^ ((col >> 1) & 3);
                *(float4*)&Bs[(row * 66 + col) * 32 + chunk * 8] = v;
            }
        }
        __syncthreads();

        #pragma unroll
        for (int tap = 0; tap < 9; ++tap) {
            const int kh = tap / 3, kw = tap % 3;
            f16x8 a[2][2], bb[2][2];
            #pragma unroll
            for (int fm = 0; fm < 2; ++fm)
                #pragma unroll
                for (int kk = 0; kk < 2; ++kk)
                    a[fm][kk] = *(const f16x8*)&As[(tap * 64 + fm * 32 + rl32) * 32 + kk * 16 + l5 * 8];
            #pragma unroll
            for (int fn = 0; fn < 2; ++fn) {
                const int colB = fn * 32 + rl32 + kw;
                const int sw = ((rl32 + kw) >> 1) & 3;
                #pragma unroll
                for (int kk = 0; kk < 2; ++kk) {
                    const int kc = kk * 2 + l5;
                    bb[fn][kk] = *(const f16x8*)&Bs[((wid + kh) * 66 + colB) * 32 + (kc ^ sw) * 8];
                }
            }
            #pragma unroll
            for (int fm = 0; fm < 2; ++fm)
                #pragma unroll
                for (int fn = 0; fn < 2; ++fn)
                    #pragma unroll
                    for (int kk = 0; kk < 2; ++kk)
                        acc[fm][fn] = __builtin_amdgcn_mfma_f32_32x32x16_f16(
                            a[fm][kk], bb[fn][kk], acc[fm][fn], 0, 0, 0);
        }
        __syncthreads();
    }

    // epilogue: 32x32 C/D layout col=lane&31, row=(reg&3)+8*(reg>>2)+4*(lane>>5)
    const int prow = r0 + wid;
    #pragma unroll
    for (int fm = 0; fm < 2; ++fm)
        #pragma unroll
        for (int fn = 0; fn < 2; ++fn) {
            const int pos = prow * 64 + fn * 32 + rl32;
            #pragma unroll
            for (int g = 0; g < 4; ++g) {
                const int co0 = cot * 64 + fm * 32 + g * 8 + l5 * 4;
                if (trans) {
                    unsigned short pk[4];
                    #pragma unroll
                    for (int rr = 0; rr < 4; ++rr)
                        pk[rr] = f2bf(fmaxf(acc[fm][fn][g * 4 + rr] + bias[co0 + rr], 0.f));
                    uint2 u;
                    u.x = (unsigned)pk[0] | ((unsigned)pk[1] << 16);
                    u.y = (unsigned)pk[2] | ((unsigned)pk[3] << 16);
                    *(uint2*)&out[((size_t)(b * N_ + pos) << 8) + co0] = u;
                } else {
                    #pragma unroll
                    for (int rr = 0; rr < 4; ++rr)
                        out[((size_t)(b * C_ + co0 + rr) << 12) + pos] =
                            f2bf(fmaxf(acc[fm][fn][g * 4 + rr] + bias[co0 + rr], 0.f));
                }
            }
        }
}

// ---------------------------------------------------------------------------
// GEMM1 (32x32x16): corrT[b][m][n] = sum_c f1x[b][m][c]*f1r[b][n][c]
// 128x128 tile, 4 waves (2x2), wave 64x64 = 2x2 frags of 32x32.
// ---------------------------------------------------------------------------
__global__ __launch_bounds__(256) void gemm_corr_k(
    const unsigned short* __restrict__ f1x, const unsigned short* __restrict__ f1r,
    float* __restrict__ corr)
{
    __shared__ alignas(16) unsigned short As[128 * 32];
    __shared__ alignas(16) unsigned short Bs[128 * 32];
    const int tid = threadIdx.x;
    const int tn = blockIdx.x, tm = blockIdx.y, b = blockIdx.z;

    const unsigned short* Ab = f1x + ((size_t)b * N_ + (size_t)tm * 128) * C_;
    const unsigned short* Bb = f1r + ((size_t)b * N_ + (size_t)tn * 128) * C_;

    const int wid = tid >> 6, lane = tid & 63;
    const int wr = wid >> 1, wc = wid & 1;
    const int rl32 = lane & 31, l5 = lane >> 5;
    const int srow = wid * 32 + (lane >> 2), sq = lane & 3;

    f32x16 acc[2][2];
    #pragma unroll
    for (int fm = 0; fm < 2; ++fm)
        #pragma unroll
        for (int fn = 0; fn < 2; ++fn)
            #pragma unroll
            for (int e = 0; e < 16; ++e) acc[fm][fn][e] = 0.f;

    for (int k0 = 0; k0 < C_; k0 += 32) {
        gload16(&Ab[(size_t)srow * C_ + k0 + sq * 8],        &As[srow * 32 + sq * 8]);
        gload16(&Ab[(size_t)(srow + 16) * C_ + k0 + sq * 8], &As[(srow + 16) * 32 + sq * 8]);
        gload16(&Bb[(size_t)srow * C_ + k0 + sq * 8],        &Bs[srow * 32 + sq * 8]);
        gload16(&Bb[(size_t)(srow + 16) * C_ + k0 + sq * 8], &Bs[(srow + 16) * 32 + sq * 8]);
        __syncthreads();
        bf16x8 a[2][2], bb[2][2];
        #pragma unroll
        for (int fm = 0; fm < 2; ++fm)
            #pragma unroll
            for (int kk = 0; kk < 2; ++kk)
                a[fm][kk] = *(const bf16x8*)&As[(wr * 64 + fm * 32 + rl32) * 32 + kk * 16 + l5 * 8];
        #pragma unroll
        for (int fn = 0; fn < 2; ++fn)
            #pragma unroll
            for (int kk = 0; kk < 2; ++kk)
                bb[fn][kk] = *(const bf16x8*)&Bs[(wc * 64 + fn * 32 + rl32) * 32 + kk * 16 + l5 * 8];
        #pragma unroll
        for (int fm = 0; fm < 2; ++fm)
            #pragma unroll
            for (int fn = 0; fn < 2; ++fn)
                #pragma unroll
                for (int kk = 0; kk < 2; ++kk)
                    acc[fm][fn] = __builtin_amdgcn_mfma_f32_32x32x16_bf16(
                        a[fm][kk], bb[fn][kk], acc[fm][fn], 0, 0, 0);
        __syncthreads();
    }

    #pragma unroll
    for (int fm = 0; fm < 2; ++fm)
        #pragma unroll
        for (int fn = 0; fn < 2; ++fn) {
            const int n = tn * 128 + wc * 64 + fn * 32 + rl32;
            #pragma unroll
            for (int g = 0; g < 4; ++g) {
                const int m0 = tm * 128 + wr * 64 + fm * 32 + g * 8 + l5 * 4;
                #pragma unroll
                for (int rr = 0; rr < 4; ++rr)
                    corr[((size_t)b * N_ + m0 + rr) * N_ + n] = acc[fm][fn][g * 4 + rr];
            }
        }
}

// ---------------------------------------------------------------------------
// Row softmax over corrT rows; reads fp32, writes bf16 packed into the
// FRONT half of the same row (in-place, block owns its row).
// ---------------------------------------------------------------------------
__global__ __launch_bounds__(256) void softmax_rows_k(float* __restrict__ corr)
{
    __shared__ float red[4];
    const int m = blockIdx.x, b = blockIdx.y;
    float* row = corr + ((size_t)b * N_ + m) * N_;
    float4* row4 = (float4*)row;
    const int tid = threadIdx.x;
    const int wid = tid >> 6, lane = tid & 63;

    float4 v[4];
    float mx = -3.0e38f;
    #pragma unroll
    for (int j = 0; j < 4; ++j) {
        v[j] = row4[tid + j * 256];
        mx = fmaxf(mx, fmaxf(fmaxf(v[j].x, v[j].y), fmaxf(v[j].z, v[j].w)));
    }
    #pragma unroll
    for (int off = 32; off; off >>= 1) mx = fmaxf(mx, __shfl_xor(mx, off));
    if (lane == 0) red[wid] = mx;
    __syncthreads();
    mx = fmaxf(fmaxf(red[0], red[1]), fmaxf(red[2], red[3]));
    __syncthreads();

    float s = 0.f;
    #pragma unroll
    for (int j = 0; j < 4; ++j) {
        v[j].x = __expf(v[j].x - mx);
        v[j].y = __expf(v[j].y - mx);
        v[j].z = __expf(v[j].z - mx);
        v[j].w = __expf(v[j].w - mx);
        s += v[j].x + v[j].y + v[j].z + v[j].w;
    }
    #pragma unroll
    for (int off = 32; off; off >>= 1) s += __shfl_xor(s, off);
    if (lane == 0) red[wid] = s;
    __syncthreads();
    s = red[0] + red[1] + red[2] + red[3];
    const float inv = 1.f / s;

    unsigned short* rb = (unsigned short*)row;
    #pragma unroll
    for (int j = 0; j < 4; ++j) {
        uint2 u;
        u.x = (unsigned)f2bf(v[j].x * inv) | ((unsigned)f2bf(v[j].y * inv) << 16);
        u.y = (unsigned)f2bf(v[j].z * inv) | ((unsigned)f2bf(v[j].w * inv) << 16);
        *(uint2*)&rb[4 * (tid + j * 256)] = u;
    }
}

// ---------------------------------------------------------------------------
// GEMM2 split-K=4: partial[s][b][c][m] = sum_{n in s-range} f2[b][c][n]*P[m][n]
// Tile 128c x 128m, 8 waves (2c x 4m). blockIdx.y = tc*4 + s. Grid 512 blocks.
// P read as bf16 (front half of fp32 corr rows, row stride 8192 ushorts).
// Partials live in the DEAD BACK HALVES of corr rows.
// ---------------------------------------------------------------------------
__global__ __launch_bounds__(512) void gemm_out_k(
    const unsigned short* __restrict__ f2, float* __restrict__ corr)
{
    __shared__ alignas(16) unsigned short As[128 * 32];
    __shared__ alignas(16) unsigned short Bs[128 * 32];
    const int tid = threadIdx.x;
    const int tm = blockIdx.x;                 // 0..31
    const int tc = blockIdx.y >> 2;            // 0..1
    const int s  = blockIdx.y & 3;             // split 0..3
    const int b  = blockIdx.z;

    const unsigned short* Ab = f2 + ((size_t)b * C_ + (size_t)tc * 128) * N_;
    const unsigned short* Bb = (const unsigned short*)corr
                             + ((size_t)b * N_ + (size_t)tm * 128) * 8192;

    const int wid = tid >> 6, lane = tid & 63;
    const int wc = wid >> 2, wm = wid & 3;
    const int rl = lane & 15, q = lane >> 4;
    const int srow = wid * 16 + (lane >> 2), sq = lane & 3;
    const int nbase = s * 1024;

    f32x4 acc[4][2];
    #pragma unroll
    for (int mi = 0; mi < 4; ++mi)
        #pragma unroll
        for (int ni = 0; ni < 2; ++ni)
            #pragma unroll
            for (int e = 0; e < 4; ++e) acc[mi][ni][e] = 0.f;

    for (int kk = 0; kk < 32; ++kk) {
        const int k0 = nbase + kk * 32;
        gload16(&Ab[(size_t)srow * N_ + k0 + sq * 8],   &As[srow * 32 + sq * 8]);
        gload16(&Bb[(size_t)srow * 8192 + k0 + sq * 8], &Bs[srow * 32 + sq * 8]);
        __syncthreads();
        bf16x8 a[4], bb[2];
        #pragma unroll
        for (int mi = 0; mi < 4; ++mi)
            a[mi] = *(const bf16x8*)&As[(wc * 64 + mi * 16 + rl) * 32 + q * 8];
        #pragma unroll
        for (int ni = 0; ni < 2; ++ni)
            bb[ni] = *(const bf16x8*)&Bs[(wm * 32 + ni * 16 + rl) * 32 + q * 8];
        #pragma unroll
        for (int mi = 0; mi < 4; ++mi)
            #pragma unroll
            for (int ni = 0; ni < 2; ++ni)
                acc[mi][ni] = __builtin_amdgcn_mfma_f32_16x16x32_bf16(a[mi], bb[ni], acc[mi][ni], 0, 0, 0);
        __syncthreads();
    }

    #pragma unroll
    for (int mi = 0; mi < 4; ++mi)
        #pragma unroll
        for (int ni = 0; ni < 2; ++ni)
            #pragma unroll
            for (int rr = 0; rr < 4; ++rr) {
                int c = tc * 128 + wc * 64 + mi * 16 + q * 4 + rr;
                int m = tm * 128 + wm * 32 + ni * 16 + rl;
                size_t e = (((size_t)(s * 2 + b) * C_ + c) << 12) + m;
                corr[(e >> 11) * 4096 + 2048 + (e & 2047)] = acc[mi][ni][rr];
            }
}

// out = gamma*(p0+p1+p2+p3) + x ; partials read back from corr back-halves
__global__ __launch_bounds__(256) void reduce_k(
    const float* __restrict__ corr, const float* __restrict__ x,
    const float* __restrict__ gamma, float* __restrict__ out)
{
    const float g = gamma[0];
    size_t i = (size_t)blockIdx.x * 256 + threadIdx.x;   // float4 index
    size_t idx = i << 2;                                  // flat f32 index (b,c,m)
    float4 sum; sum.x = 0.f; sum.y = 0.f; sum.z = 0.f; sum.w = 0.f;
    #pragma unroll
    for (int sp = 0; sp < 4; ++sp) {
        size_t e = (size_t)sp * 2097152 + idx;
        float4 v = *(const float4*)&corr[(e >> 11) * 4096 + 2048 + (e & 2047)];
        sum.x += v.x; sum.y += v.y; sum.z += v.z; sum.w += v.w;
    }
    float4 xv = ((const float4*)x)[i];
    float4 o;
    o.x = sum.x * g + xv.x;
    o.y = sum.y * g + xv.y;
    o.z = sum.z * g + xv.z;
    o.w = sum.w * g + xv.w;
    ((float4*)out)[i] = o;
}

extern "C" void kernel_launch(void* const* d_in, const int* in_sizes, int n_in,
                              void* d_out, int out_size, void* d_ws, size_t ws_size,
                              hipStream_t stream) {
    const float* x     = (const float*)d_in[0];
    const float* ref_x = (const float*)d_in[1];
    const float* w1    = (const float*)d_in[2];
    const float* b1    = (const float*)d_in[3];
    const float* w2    = (const float*)d_in[4];
    const float* b2    = (const float*)d_in[5];
    const float* gamma = (const float*)d_in[6];
    float* out = (float*)d_out;

    char* ws = (char*)d_ws;
    size_t off = 0;
    auto nxt = [&](size_t bytes) {
        char* p = ws + off;
        off += (bytes + 255) & ~(size_t)255;
        return p;
    };
    unsigned short* f1x = (unsigned short*)nxt((size_t)B_ * N_ * C_ * 2);  // bf16 [b][m][c]
    unsigned short* f1r = (unsigned short*)nxt((size_t)B_ * N_ * C_ * 2);  // bf16 [b][n][c]
    unsigned short* f2  = (unsigned short*)nxt((size_t)B_ * N_ * C_ * 2);  // bf16 [b][c][n]
    unsigned short* xtx = (unsigned short*)nxt((size_t)B_ * N_ * C_ * 2);  // fp16 [b][p][c]
    unsigned short* xtr = (unsigned short*)nxt((size_t)B_ * N_ * C_ * 2);  // fp16 [b][p][c]
    unsigned short* w1h = (unsigned short*)nxt((size_t)9 * C_ * C_ * 2);   // fp16 [tap][o][i]
    unsigned short* w2h = (unsigned short*)nxt((size_t)9 * C_ * C_ * 2);   // fp16 [tap][o][i]
    float* corr = (float*)nxt((size_t)B_ * N_ * N_ * 4);                   // fp32 corrT [b][m][n]

    cvt_x_k<<<dim3(64, 4, 4), 256, 0, stream>>>(x, ref_x, xtx, xtr);
    cvt_w_k<<<4608, 256, 0, stream>>>(w1, w2, w1h, w2h);

    conv_mfma_k<<<dim3(16, 4, 6), 256, 0, stream>>>(xtx, xtr, w1h, w2h, b1, b2,
                                                    f1x, f1r, f2);

    gemm_corr_k<<<dim3(32, 32, B_), 256, 0, stream>>>(f1x, f1r, corr);
    softmax_rows_k<<<dim3(N_, B_), 256, 0, stream>>>(corr);
    gemm_out_k<<<dim3(32, 8, B_), 512, 0, stream>>>(f2, corr);
    reduce_k<<<2048, 256, 0, stream>>>(corr, x, gamma, out);
}